// Round 12
// baseline (50.028 us; speedup 1.0000x reference)
//
#include <hip/hip_runtime.h>
#include <hip/hip_bf16.h>

#define M_DIM 8192
#define N_DIM 8192

typedef short short8 __attribute__((ext_vector_type(8)));
typedef float f32x4 __attribute__((ext_vector_type(4)));

static __device__ __forceinline__ short f2bf(float f) {
    __hip_bfloat16 h = __float2bfloat16(f);   // RNE convert
    union { __hip_bfloat16 h; short s; } u;
    u.h = h;
    return u.s;
}

// Fused single kernel: C[m,n] = dq[m,:] @ act[:,n].
// R12: block tile 128 rows x 256 cols. B lives in LDS (bf16, col-major,
// XOR-swizzled) built once per block (grid 512 = all blocks resident), which
// frees the VGPRs that killed R10. Wave owns 32 rows x 256 cols; epilogue
// stores ONE FULL 1KB contiguous row segment per store instruction
// (R7: 128B/row-visit = 59us, R8/R11: 512B = 49.8us -> this is the next step
// of the only lever that has consistently worked). Plain stores (R11 win).
// No block barriers after prologue; fire-and-forget stores overlap compute.
__global__ __launch_bounds__(256, 2) void gemm_dq(const float* __restrict__ scale,
                                                  const int* __restrict__ offset,
                                                  const int* __restrict__ weight,
                                                  const float* __restrict__ act,
                                                  float* __restrict__ C) {
    // B: [col][k] bf16, 256*64*2 = 32 KB. Chunk (16B = 8 k's) swizzled by col.
    __shared__ short blds[256 * 64];
    // Epilogue staging: per-wave 8 rows x 258 f32 = 8.25 KB, 33 KB total.
    __shared__ float epi[4][8 * 258];

    const int tid  = threadIdx.x;
    const int lane = tid & 63;
    const int wid  = tid >> 6;
    const int l15  = lane & 15;
    const int l4   = lane >> 4;

    const int bn = (int)blockIdx.x & 31;      // 32 n-tiles of 256
    const int mg = (int)blockIdx.x >> 5;      // 16 m-groups of 512 rows
    const int n0 = bn * 256;

    // ---- Prologue: build B in LDS. act row k, cols n0+tid (1KB coalesced per
    // iter). LDS byte addr: col*128 + ((k>>3) ^ (col&7))*16 + (k&7)*2.
    char* bb = reinterpret_cast<char*>(blds);
    for (int k = 0; k < 64; ++k) {
        const float v = act[(size_t)k * N_DIM + (n0 + tid)];
        const int byteoff = tid * 128 + ((((k >> 3) ^ (tid & 7))) << 4) + ((k & 7) << 1);
        *reinterpret_cast<short*>(bb + byteoff) = f2bf(v);
    }
    __syncthreads();   // only block barrier in the kernel

    float* ws = &epi[wid][0];
    const int rot = ((mg >> 3) & 1) * 2;      // desync co-resident block pair

    for (int ti = 0; ti < 4; ++ti) {
        const int t  = (ti + rot) & 3;
        const int mb = mg * 512 + t * 128 + wid * 32;   // wave's 32-row slab

        #pragma unroll
        for (int fm = 0; fm < 2; ++fm) {
            const int m0 = mb + fm * 16;

            // A fragments: dequantize 4-bit weights into registers.
            // Lane: row m = m0+l15, k = kh*32+l4*8+j => group g = kh*4+l4.
            short8 afrag[2];
            #pragma unroll
            for (int kh = 0; kh < 2; ++kh) {
                const int g = kh * 4 + l4;
                const int m = m0 + l15;
                const unsigned w = (unsigned)weight[m * 8 + g];
                const float   s = scale[m * 8 + g];
                const int   off = (int)(((unsigned)offset[m] >> (4 * g)) & 15u);
                short8 a;
                #pragma unroll
                for (int j = 0; j < 8; ++j) {
                    const int wv = (int)((w >> (4 * j)) & 15u);
                    a[j] = f2bf(s * (float)(wv - off));
                }
                afrag[kh] = a;
            }

            // MFMA: 16 rows x 256 cols = 16 fn-fragments x 2 k-halves.
            // B fragment (kh,fn): 16B LDS read at col*128 + ((kh*4+l4)^(col&7))*16.
            f32x4 acc[16] = {};
            #pragma unroll
            for (int fn = 0; fn < 16; ++fn) {
                const int col  = fn * 16 + l15;
                const int base = col * 128;
                const short8 b0 = *reinterpret_cast<const short8*>(
                    bb + base + (((0 + l4) ^ (col & 7)) << 4));
                const short8 b1 = *reinterpret_cast<const short8*>(
                    bb + base + (((4 + l4) ^ (col & 7)) << 4));
                acc[fn] = __builtin_amdgcn_mfma_f32_16x16x32_bf16(
                    afrag[0], b0, acc[fn], 0, 0, 0);
                acc[fn] = __builtin_amdgcn_mfma_f32_16x16x32_bf16(
                    afrag[1], b1, acc[fn], 0, 0, 0);
            }

            // Epilogue: two j-rounds of 8 rows. Stage 8x256 (pad 258), then
            // each store instr = 64 lanes x 16B = ONE full 1KB row segment.
            // C/D layout: col = fn*16+l15, row16 = l4*4 + j.
            #pragma unroll
            for (int jr = 0; jr < 2; ++jr) {
                #pragma unroll
                for (int fn = 0; fn < 16; ++fn) {
                    const int col = fn * 16 + l15;
                    #pragma unroll
                    for (int jj = 0; jj < 2; ++jj) {
                        const int r8 = l4 * 2 + jj;
                        ws[r8 * 258 + col] = acc[fn][jr * 2 + jj];
                    }
                }
                // wave-internal RAW on LDS (per-wave DS pipe is in-order)
                asm volatile("s_waitcnt lgkmcnt(0)" ::: "memory");
                #pragma unroll
                for (int s = 0; s < 8; ++s) {
                    const int row16 = (s >> 1) * 4 + jr * 2 + (s & 1);
                    const f32x4 v = *reinterpret_cast<const f32x4*>(&ws[s * 258 + lane * 4]);
                    *reinterpret_cast<f32x4*>(
                        &C[(size_t)(m0 + row16) * N_DIM + n0 + lane * 4]) = v;
                }
            }
        }
    }
}

extern "C" void kernel_launch(void* const* d_in, const int* in_sizes, int n_in,
                              void* d_out, int out_size, void* d_ws, size_t ws_size,
                              hipStream_t stream) {
    const float* scale  = (const float*)d_in[0];
    const int*   offset = (const int*)d_in[1];
    const int*   weight = (const int*)d_in[2];
    const float* act    = (const float*)d_in[3];
    float* out  = (float*)d_out;

    gemm_dq<<<512, 256, 0, stream>>>(scale, offset, weight, act, out);
}

// Round 13
// 49.614 us; speedup vs baseline: 1.0083x; 1.0083x over previous
//
#include <hip/hip_runtime.h>
#include <hip/hip_bf16.h>

#define M_DIM 8192
#define N_DIM 8192

typedef short short8 __attribute__((ext_vector_type(8)));
typedef float f32x4 __attribute__((ext_vector_type(4)));

static __device__ __forceinline__ short f2bf(float f) {
    __hip_bfloat16 h = __float2bfloat16(f);   // RNE convert
    union { __hip_bfloat16 h; short s; } u;
    u.h = h;
    return u.s;
}

// Fused single kernel: C[m,n] = dq[m,:] @ act[:,n].
// R11 STRUCTURE (49.8 us best): grid 512 (2 blocks/CU, zero tail), bn fixed
// per block, B fragments in registers built once from f32 act, 8 M-tiles,
// no block barriers, fire-and-forget PLAIN stores, wave owns 32 rows x 128
// cols, 512B/row write bursts via per-wave LDS staging.
// R13 single-variable change: LOCKSTEP BAND WALK. m0 = (ti*8 + mg)*128 so at
// any instant ALL 512 blocks write inside one contiguous 1024-row (32 MB)
// band, sweeping C top-to-bottom like the 7 TB/s fill kernel's dense linear
// stream (was: each mg-group scattered in its own private 512-row region).
__global__ __launch_bounds__(256, 2) void gemm_dq(const float* __restrict__ scale,
                                                  const int* __restrict__ offset,
                                                  const int* __restrict__ weight,
                                                  const float* __restrict__ act,
                                                  float* __restrict__ C) {
    // wave-private staging: 16 rows x 132 cols f32 (pad -> <=2-way conflicts)
    __shared__ float cs[4][16 * 132];

    const int tid  = threadIdx.x;
    const int lane = tid & 63;
    const int wid  = tid >> 6;
    const int l15  = lane & 15;
    const int l4   = lane >> 4;

    const int bn = (int)blockIdx.x & 63;      // 64 n-tiles of 128
    const int mg = (int)blockIdx.x >> 6;      // 8 band-slots
    const int n0 = bn * 128;                  // block's 128-col extent

    // ---- B fragments: built ONCE from act [64, 8192] f32 (L2/L3-hot),
    // converted to bf16 in-register; reused across all 8 m-tiles.
    // Element j of fragment (kh,fn) = act[kh*32 + l4*8 + j][n0 + fn*16 + l15].
    short8 bfrag[2][8];
    #pragma unroll
    for (int kh = 0; kh < 2; ++kh) {
        #pragma unroll
        for (int fn = 0; fn < 8; ++fn) {
            const float* ap = act + (size_t)(kh * 32 + l4 * 8) * N_DIM + (n0 + fn * 16 + l15);
            short8 b;
            #pragma unroll
            for (int j = 0; j < 8; ++j) {
                b[j] = f2bf(ap[(size_t)j * N_DIM]);
            }
            bfrag[kh][fn] = b;
        }
    }

    float* ws = &cs[wid][0];

    #pragma unroll 2
    for (int ti = 0; ti < 8; ++ti) {
        // LOCKSTEP BANDS: at step ti the whole grid writes rows
        // [ti*1024, ti*1024+1024) -- one contiguous 32 MB region.
        const int m0 = (ti * 8 + mg) * 128 + wid * 32;   // wave's 32-row slab

        // ---- Process the wave's two 16-row fragments one at a time
        // (keeps acc live-set at 32 VGPR).
        #pragma unroll
        for (int fm = 0; fm < 2; ++fm) {
            // A fragments: dequantize 4-bit weights directly into registers.
            // Lane: row m = m0+fm*16+(lane&15), k = kh*32+(lane>>4)*8+j
            // => group g = kh*4+(lane>>4): one word, one scale, one offset nibble.
            short8 afrag[2];
            #pragma unroll
            for (int kh = 0; kh < 2; ++kh) {
                const int g = kh * 4 + l4;
                const int m = m0 + fm * 16 + l15;
                const unsigned w = (unsigned)weight[m * 8 + g];
                const float   s = scale[m * 8 + g];
                const int   off = (int)(((unsigned)offset[m] >> (4 * g)) & 15u);
                short8 a;
                #pragma unroll
                for (int j = 0; j < 8; ++j) {
                    const int wv = (int)((w >> (4 * j)) & 15u);
                    a[j] = f2bf(s * (float)(wv - off));
                }
                afrag[kh] = a;
            }

            // MFMA: 16 rows x 128 cols = 8 fn-fragments x 2 k-halves
            f32x4 acc[8] = {};
            #pragma unroll
            for (int fn = 0; fn < 8; ++fn) {
                acc[fn] = __builtin_amdgcn_mfma_f32_16x16x32_bf16(
                    afrag[0], bfrag[0][fn], acc[fn], 0, 0, 0);
                acc[fn] = __builtin_amdgcn_mfma_f32_16x16x32_bf16(
                    afrag[1], bfrag[1][fn], acc[fn], 0, 0, 0);
            }

            // Stage 16x128 into padded LDS (2-way bank aliasing = free).
            // C/D layout: col = fn*16 + l15, row16 = l4*4 + j.
            #pragma unroll
            for (int fn = 0; fn < 8; ++fn) {
                const int col = fn * 16 + l15;
                #pragma unroll
                for (int j = 0; j < 4; ++j) {
                    const int row16 = l4 * 4 + j;
                    ws[row16 * 132 + col] = acc[fn][j];
                }
            }
            // wave-internal RAW on LDS (per-wave DS pipe is in-order)
            asm volatile("s_waitcnt lgkmcnt(0)" ::: "memory");

            // Readback + store: each instr = 2 rows x 512B contiguous; rows
            // ascend. Plain stores (R11 win: drain via L2 eviction engine).
            #pragma unroll
            for (int s = 0; s < 8; ++s) {
                const int row16 = s * 2 + (lane >> 5);
                const int c4    = (lane & 31) * 4;
                const f32x4 v = *reinterpret_cast<const f32x4*>(&ws[row16 * 132 + c4]);
                const size_t gr = (size_t)(m0 + fm * 16 + row16);
                *reinterpret_cast<f32x4*>(&C[gr * N_DIM + n0 + c4]) = v;
            }
        }
    }
}

extern "C" void kernel_launch(void* const* d_in, const int* in_sizes, int n_in,
                              void* d_out, int out_size, void* d_ws, size_t ws_size,
                              hipStream_t stream) {
    const float* scale  = (const float*)d_in[0];
    const int*   offset = (const int*)d_in[1];
    const int*   weight = (const int*)d_in[2];
    const float* act    = (const float*)d_in[3];
    float* out  = (float*)d_out;

    gemm_dq<<<512, 256, 0, stream>>>(scale, offset, weight, act, out);
}